// Round 1
// baseline (415.864 us; speedup 1.0000x reference)
//
#include <hip/hip_runtime.h>
#include <math.h>

// Problem constants (match reference)
#define N_RAYS    131072
#define N_SAMPLES 128
#define BIG_DIST  1e10f
#define EPS       1e-10f

// Output layout (flat concat, all fp32):
//   rgb_map   [R,3]   offset 0
//   disp_map  [R]     offset 393216
//   acc_map   [R]     offset 524288
//   weights   [R,S]   offset 655360
//   depth_map [R]     offset 17432576
#define OFF_RGB    0
#define OFF_DISP   393216
#define OFF_ACC    524288
#define OFF_W      655360
#define OFF_DEPTH  17432576

// v2: TWO rays per wave (32 lanes each), FOUR samples per lane.
//   - segmented inclusive prefix-product scan over 32-lane halves (5 shfl_up)
//   - 5 reductions over 32-lane halves (5 shfl_xor each; xor masks <32 never
//     cross the half-wave boundary, so no width arg needed)
//   - per-wave shuffle count: 31 for 2 rays (vs 36 for 1 ray before)
//   - wider loads: z as float4, raw as 4x float4 (64 B/lane), weights float4
__global__ __launch_bounds__(256) void nerf_render_scan2_kernel(
    const float4* __restrict__ raw,     // [R, S] rgb+sigma
    const float*  __restrict__ z_vals,  // [R, S]
    const float*  __restrict__ rays_d,  // [R, 3]
    float* __restrict__ out)
{
    const int tid  = blockIdx.x * blockDim.x + threadIdx.x;
    const int wave = tid >> 6;
    const int lane = threadIdx.x & 63;
    const int sub  = lane & 31;                 // position within half-wave
    const int r    = (wave << 1) | (lane >> 5); // 2 rays per wave
    if (r >= N_RAYS) return;

    // ---- loads (contiguous 64 B per lane; halves cover adjacent rays) ----
    const float4* rawr = raw + (size_t)r * N_SAMPLES + 4 * sub;
    const float4 rv0 = rawr[0];
    const float4 rv1 = rawr[1];
    const float4 rv2 = rawr[2];
    const float4 rv3 = rawr[3];

    const float4 z = ((const float4*)(z_vals + (size_t)r * N_SAMPLES))[sub];
    // z[4*sub+4] lives in the next lane's z.x (within the 32-lane segment)
    const float znext = __shfl_down(z.x, 1, 32);

    const float dxx = rays_d[3 * r + 0];
    const float dyy = rays_d[3 * r + 1];
    const float dzz = rays_d[3 * r + 2];
    const float nrm = sqrtf(dxx * dxx + dyy * dyy + dzz * dzz);

    // ---- per-sample alpha ----
    const float d0 = (z.y - z.x) * nrm;
    const float d1 = (z.z - z.y) * nrm;
    const float d2 = (z.w - z.z) * nrm;
    const float d3 = (sub == 31) ? (BIG_DIST * nrm) : ((znext - z.w) * nrm);

    const float a0 = 1.0f - __expf(-fmaxf(rv0.w, 0.0f) * d0);
    const float a1 = 1.0f - __expf(-fmaxf(rv1.w, 0.0f) * d1);
    const float a2 = 1.0f - __expf(-fmaxf(rv2.w, 0.0f) * d2);
    const float a3 = 1.0f - __expf(-fmaxf(rv3.w, 0.0f) * d3);

    const float f0 = 1.0f - a0 + EPS;    // per-sample transmittance factors
    const float f1 = 1.0f - a1 + EPS;
    const float f2 = 1.0f - a2 + EPS;
    const float f3 = 1.0f - a3 + EPS;
    float sp = f0 * f1 * f2 * f3;        // per-lane product

    // ---- inclusive prefix product over the 32-lane segment (5 steps) ----
#pragma unroll
    for (int off = 1; off < 32; off <<= 1) {
        const float t = __shfl_up(sp, off, 32);
        sp *= (sub >= off) ? t : 1.0f;
    }
    // exclusive prefix: shift by one lane within the segment
    float Texc = __shfl_up(sp, 1, 32);
    if (sub == 0) Texc = 1.0f;

    const float T0 = Texc;
    const float T1 = T0 * f0;
    const float T2 = T1 * f1;
    const float T3 = T2 * f2;
    const float w0 = a0 * T0;
    const float w1 = a1 * T1;
    const float w2 = a2 * T2;
    const float w3 = a3 * T3;

    // ---- weights store (coalesced float4) ----
    ((float4*)(out + OFF_W + (size_t)r * N_SAMPLES))[sub] =
        make_float4(w0, w1, w2, w3);

    // ---- per-lane partials for the 5 reductions ----
    const float sr0 = __builtin_amdgcn_rcpf(1.0f + __expf(-rv0.x));
    const float sg0 = __builtin_amdgcn_rcpf(1.0f + __expf(-rv0.y));
    const float sb0 = __builtin_amdgcn_rcpf(1.0f + __expf(-rv0.z));
    const float sr1 = __builtin_amdgcn_rcpf(1.0f + __expf(-rv1.x));
    const float sg1 = __builtin_amdgcn_rcpf(1.0f + __expf(-rv1.y));
    const float sb1 = __builtin_amdgcn_rcpf(1.0f + __expf(-rv1.z));
    const float sr2 = __builtin_amdgcn_rcpf(1.0f + __expf(-rv2.x));
    const float sg2 = __builtin_amdgcn_rcpf(1.0f + __expf(-rv2.y));
    const float sb2 = __builtin_amdgcn_rcpf(1.0f + __expf(-rv2.z));
    const float sr3 = __builtin_amdgcn_rcpf(1.0f + __expf(-rv3.x));
    const float sg3 = __builtin_amdgcn_rcpf(1.0f + __expf(-rv3.y));
    const float sb3 = __builtin_amdgcn_rcpf(1.0f + __expf(-rv3.z));

    float cr    = w0 * sr0 + w1 * sr1 + w2 * sr2 + w3 * sr3;
    float cg    = w0 * sg0 + w1 * sg1 + w2 * sg2 + w3 * sg3;
    float cb    = w0 * sb0 + w1 * sb1 + w2 * sb2 + w3 * sb3;
    float depth = w0 * z.x + w1 * z.y + w2 * z.z + w3 * z.w;
    float acc   = w0 + w1 + w2 + w3;

    // ---- segmented butterfly reduction (xor masks <32 stay in the half) ----
#pragma unroll
    for (int m = 16; m > 0; m >>= 1) {
        cr    += __shfl_xor(cr, m);
        cg    += __shfl_xor(cg, m);
        cb    += __shfl_xor(cb, m);
        depth += __shfl_xor(depth, m);
        acc   += __shfl_xor(acc, m);
    }

    if (sub == 0) {
        out[OFF_RGB + 3 * r + 0] = cr;
        out[OFF_RGB + 3 * r + 1] = cg;
        out[OFF_RGB + 3 * r + 2] = cb;
        out[OFF_ACC + r]   = acc;
        out[OFF_DEPTH + r] = depth;
        out[OFF_DISP + r]  = 1.0f / fmaxf(EPS, depth / acc);
    }
}

extern "C" void kernel_launch(void* const* d_in, const int* in_sizes, int n_in,
                              void* d_out, int out_size, void* d_ws, size_t ws_size,
                              hipStream_t stream) {
    const float4* raw    = (const float4*)d_in[0];
    const float*  z_vals = (const float*)d_in[1];
    const float*  rays_d = (const float*)d_in[2];
    float* out = (float*)d_out;

    const int block = 256;                        // 4 waves = 8 rays per block
    const int rays_per_block = (block / 64) * 2;  // 2 rays per wave
    const int grid = N_RAYS / rays_per_block;     // 16384 blocks
    nerf_render_scan2_kernel<<<grid, block, 0, stream>>>(raw, z_vals, rays_d, out);
}